// Round 1
// baseline (591.015 us; speedup 1.0000x reference)
//
#include <hip/hip_runtime.h>
#include <hip/hip_bf16.h>

// Problem constants
#define BB 64
#define II 1152
#define OO 32
#define DD 8
#define HH 16

// Decomposition
#define IC   9     // i-values per block          (NIC * IC == II)
#define NIC  128   // i-chunks
#define NBB  16    // b per block
#define NBG  4     // b-groups (NBG * NBB == BB)
#define NJB  4     // b per thread
#define WS   132   // padded LDS row stride for W[o][.] (128 + 4 to break bank conflicts)

// Pass kernel: one routing iteration.
//   PASS==0: coupling uniform (softmax of zeros)
//   PASS==1: logit = v0 . u_hat
//   PASS==2: logit = (v0+v1) . u_hat   (logits are linear in v -> sum the v's)
// Thread layout: tid = o + 32*hh + 64*bq  (o: capsule-out, hh: h-half, bq: b-quad)
// Each thread handles NJB=4 b's for one (o, h-half); softmax-over-o is in-wave.
template<int PASS>
__global__ __launch_bounds__(256, 2)
void pass_kernel(const float* __restrict__ u, const float* __restrict__ w,
                 const float* __restrict__ pv0, const float* __restrict__ pv1,
                 float* __restrict__ s_out)
{
    __shared__ float Wsh[OO * WS];      // 4224 floats (16.5 KB), padded rows
    __shared__ float Ush[NBB * DD];     // 128 floats

    const int tid   = threadIdx.x;
    const int o     = tid & 31;
    const int hh    = (tid >> 5) & 1;
    const int bq    = tid >> 6;          // 0..3
    const int bbase = blockIdx.y * NBB;
    const int i0    = blockIdx.x * IC;
    const int hofs  = hh * 8;

    // vsum = sum of previous v's for this thread's (b, o, h-half) — constant over i
    float vsum[NJB][8];
    if (PASS >= 1) {
        #pragma unroll
        for (int jb = 0; jb < NJB; jb++) {
            const int b = bbase + bq * NJB + jb;
            const float* p = pv0 + ((b * OO + o) * HH + hofs);
            float4 a = *(const float4*)p;
            float4 c = *(const float4*)(p + 4);
            vsum[jb][0] = a.x; vsum[jb][1] = a.y; vsum[jb][2] = a.z; vsum[jb][3] = a.w;
            vsum[jb][4] = c.x; vsum[jb][5] = c.y; vsum[jb][6] = c.z; vsum[jb][7] = c.w;
            if (PASS == 2) {
                const float* q = pv1 + ((b * OO + o) * HH + hofs);
                float4 a2 = *(const float4*)q;
                float4 c2 = *(const float4*)(q + 4);
                vsum[jb][0] += a2.x; vsum[jb][1] += a2.y; vsum[jb][2] += a2.z; vsum[jb][3] += a2.w;
                vsum[jb][4] += c2.x; vsum[jb][5] += c2.y; vsum[jb][6] += c2.z; vsum[jb][7] += c2.w;
            }
        }
    }

    float sacc[NJB][8];
    #pragma unroll
    for (int jb = 0; jb < NJB; jb++) {
        #pragma unroll
        for (int h2 = 0; h2 < 8; h2++) sacc[jb][h2] = 0.f;
    }

    for (int ii = 0; ii < IC; ii++) {
        const int i = i0 + ii;
        __syncthreads();   // protect LDS reuse from previous iteration

        // Stage W[i] (4096 floats) into padded LDS rows; coalesced 16B/lane loads.
        {
            const float* wg = w + (size_t)i * (OO * DD * HH);
            #pragma unroll
            for (int j = 0; j < 4; j++) {
                const int c   = tid + j * 256;      // chunk of 4 floats, 0..1023
                float4 val    = *(const float4*)(wg + c * 4);
                const int orow = c >> 5;            // 32 chunks per 128-float row
                const int rr   = (c & 31) * 4;
                *(float4*)&Wsh[orow * WS + rr] = val;
            }
            // Stage u[bbase..bbase+16, i, 0..8]
            if (tid < NBB * 2) {
                const int bl = tid >> 1, q4 = (tid & 1) * 4;
                *(float4*)&Ush[bl * DD + q4] =
                    *(const float4*)(u + ((size_t)(bbase + bl) * II + i) * DD + q4);
            }
        }
        __syncthreads();

        // u values to registers (broadcast reads, wave-uniform address)
        float us[NJB][8];
        #pragma unroll
        for (int jb = 0; jb < NJB; jb++) {
            const int bl = bq * NJB + jb;
            float4 a = *(const float4*)&Ush[bl * DD];
            float4 c = *(const float4*)&Ush[bl * DD + 4];
            us[jb][0] = a.x; us[jb][1] = a.y; us[jb][2] = a.z; us[jb][3] = a.w;
            us[jb][4] = c.x; us[jb][5] = c.y; us[jb][6] = c.z; us[jb][7] = c.w;
        }

        // u_hat[b, i, o, h-half] = sum_d u[b,i,d] * W[i,o,d,h]
        float uh[NJB][8];
        #pragma unroll
        for (int jb = 0; jb < NJB; jb++) {
            #pragma unroll
            for (int h2 = 0; h2 < 8; h2++) uh[jb][h2] = 0.f;
        }
        #pragma unroll
        for (int d = 0; d < DD; d++) {
            const float* wp = &Wsh[o * WS + d * HH + hofs];
            float4 wa = *(const float4*)wp;
            float4 wb = *(const float4*)(wp + 4);
            const float wv[8] = {wa.x, wa.y, wa.z, wa.w, wb.x, wb.y, wb.z, wb.w};
            #pragma unroll
            for (int jb = 0; jb < NJB; jb++) {
                #pragma unroll
                for (int h2 = 0; h2 < 8; h2++)
                    uh[jb][h2] = fmaf(us[jb][d], wv[h2], uh[jb][h2]);
            }
        }

        // coupling coefficients
        float cc[NJB];
        if (PASS == 0) {
            #pragma unroll
            for (int jb = 0; jb < NJB; jb++) cc[jb] = 1.0f / 32.0f;
        } else {
            #pragma unroll
            for (int jb = 0; jb < NJB; jb++) {
                float lg = 0.f;
                #pragma unroll
                for (int h2 = 0; h2 < 8; h2++)
                    lg = fmaf(vsum[jb][h2], uh[jb][h2], lg);
                lg += __shfl_xor(lg, 32, 64);          // combine h-halves
                // softmax over o (lanes 0..31 within each half). |lg| <= ~6 -> no max-sub needed.
                const float e = __expf(lg);
                float se = e;
                #pragma unroll
                for (int off = 16; off >= 1; off >>= 1)
                    se += __shfl_xor(se, off, 64);
                cc[jb] = e / se;
            }
        }

        // s accumulation over i (register-resident)
        #pragma unroll
        for (int jb = 0; jb < NJB; jb++) {
            #pragma unroll
            for (int h2 = 0; h2 < 8; h2++)
                sacc[jb][h2] = fmaf(cc[jb], uh[jb][h2], sacc[jb][h2]);
        }
    }

    // cross-block reduction of s (64 adds per address per pass, low contention)
    #pragma unroll
    for (int jb = 0; jb < NJB; jb++) {
        const int b = bbase + bq * NJB + jb;
        float* p = s_out + ((b * OO + o) * HH + hofs);
        #pragma unroll
        for (int h2 = 0; h2 < 8; h2++)
            atomicAdd(p + h2, sacc[jb][h2]);
    }
}

// squash(s) = (|s|^2/(1+|s|^2)) * s / sqrt(|s|^2 + 1e-8), per (b,o) row of 16
__global__ __launch_bounds__(256)
void squash_kernel(const float* __restrict__ s, float* __restrict__ v)
{
    const int t = blockIdx.x * blockDim.x + threadIdx.x;
    if (t >= BB * OO) return;
    const float4* sp = (const float4*)(s + t * HH);
    float4 a = sp[0], b = sp[1], c = sp[2], d = sp[3];
    float sq = a.x*a.x + a.y*a.y + a.z*a.z + a.w*a.w
             + b.x*b.x + b.y*b.y + b.z*b.z + b.w*b.w
             + c.x*c.x + c.y*c.y + c.z*c.z + c.w*c.w
             + d.x*d.x + d.y*d.y + d.z*d.z + d.w*d.w;
    const float scale = (sq / (1.f + sq)) * rsqrtf(sq + 1e-8f);
    a.x *= scale; a.y *= scale; a.z *= scale; a.w *= scale;
    b.x *= scale; b.y *= scale; b.z *= scale; b.w *= scale;
    c.x *= scale; c.y *= scale; c.z *= scale; c.w *= scale;
    d.x *= scale; d.y *= scale; d.z *= scale; d.w *= scale;
    float4* vp = (float4*)(v + t * HH);
    vp[0] = a; vp[1] = b; vp[2] = c; vp[3] = d;
}

extern "C" void kernel_launch(void* const* d_in, const int* in_sizes, int n_in,
                              void* d_out, int out_size, void* d_ws, size_t ws_size,
                              hipStream_t stream)
{
    (void)in_sizes; (void)n_in; (void)out_size; (void)ws_size;
    const float* u = (const float*)d_in[0];
    const float* w = (const float*)d_in[1];
    float* out = (float*)d_out;

    const int BOH = BB * OO * HH;            // 32768
    float* s0 = (float*)d_ws;                // pass-0 s accumulator
    float* s1 = s0 + BOH;                    // pass-1 s accumulator
    float* v0 = s1 + BOH;                    // squash(s0)
    float* v1 = v0 + BOH;                    // squash(s1)
    // total ws use: 4 * 128 KB = 512 KB

    // zero the atomic accumulators (ws and d_out are poisoned 0xAA each call)
    hipMemsetAsync(d_ws, 0, 2 * BOH * sizeof(float), stream);
    hipMemsetAsync(d_out, 0, BOH * sizeof(float), stream);

    const dim3 grid(NIC, NBG), blk(256);
    const int sq_blocks = (BB * OO + 255) / 256;

    pass_kernel<0><<<grid, blk, 0, stream>>>(u, w, nullptr, nullptr, s0);
    squash_kernel<<<sq_blocks, 256, 0, stream>>>(s0, v0);
    pass_kernel<1><<<grid, blk, 0, stream>>>(u, w, v0, nullptr, s1);
    squash_kernel<<<sq_blocks, 256, 0, stream>>>(s1, v1);
    pass_kernel<2><<<grid, blk, 0, stream>>>(u, w, v0, v1, out);   // atomics into d_out
    squash_kernel<<<sq_blocks, 256, 0, stream>>>(out, out);        // in-place squash
}

// Round 2
// 163.266 us; speedup vs baseline: 3.6200x; 3.6200x over previous
//
#include <hip/hip_runtime.h>
#include <hip/hip_bf16.h>

// Problem constants
#define BB 64
#define II 1152
#define OO 32
#define DD 8
#define HH 16
#define BOH (BB * OO * HH)   // 32768

// Decomposition
#define IC   9     // i-values per block          (NIC * IC == II)
#define NIC  128   // i-chunks
#define NBB  16    // b per block
#define NBG  4     // b-groups (NBG * NBB == BB)
#define NJB  4     // b per thread
#define WS   132   // padded LDS row stride for W[o][.] (128 + 4 breaks the 32-way conflict)

// Pass kernel: one routing iteration.
//   PASS==0: coupling uniform (softmax of zeros)
//   PASS==1: logit = v0 . u_hat
//   PASS==2: logit = (v0+v1) . u_hat   (logits are linear in v -> sum the v's)
// Thread layout: tid = o + 32*hh + 64*bq  (o: capsule-out, hh: h-half, bq: b-quad)
// ATOMIC=false: plain-store per-chunk partial s to out[ic][b][o][h]  (two-stage reduce)
// ATOMIC=true : atomicAdd into out[b][o][h]                          (small-ws fallback)
template<int PASS, bool ATOMIC>
__global__ __launch_bounds__(256, 2)
void pass_kernel(const float* __restrict__ u, const float* __restrict__ w,
                 const float* __restrict__ pv0, const float* __restrict__ pv1,
                 float* __restrict__ out)
{
    __shared__ float Wsh[OO * WS];      // 16.5 KB, padded rows
    __shared__ float Ush[NBB * DD];     // 128 floats

    const int tid   = threadIdx.x;
    const int o     = tid & 31;
    const int hh    = (tid >> 5) & 1;
    const int bq    = tid >> 6;          // 0..3
    const int bbase = blockIdx.y * NBB;
    const int i0    = blockIdx.x * IC;
    const int hofs  = hh * 8;

    // vsum = sum of previous v's for this thread's (b, o, h-half) — constant over i
    float vsum[NJB][8];
    if (PASS >= 1) {
        #pragma unroll
        for (int jb = 0; jb < NJB; jb++) {
            const int b = bbase + bq * NJB + jb;
            const float* p = pv0 + ((b * OO + o) * HH + hofs);
            float4 a = *(const float4*)p;
            float4 c = *(const float4*)(p + 4);
            vsum[jb][0] = a.x; vsum[jb][1] = a.y; vsum[jb][2] = a.z; vsum[jb][3] = a.w;
            vsum[jb][4] = c.x; vsum[jb][5] = c.y; vsum[jb][6] = c.z; vsum[jb][7] = c.w;
            if (PASS == 2) {
                const float* q = pv1 + ((b * OO + o) * HH + hofs);
                float4 a2 = *(const float4*)q;
                float4 c2 = *(const float4*)(q + 4);
                vsum[jb][0] += a2.x; vsum[jb][1] += a2.y; vsum[jb][2] += a2.z; vsum[jb][3] += a2.w;
                vsum[jb][4] += c2.x; vsum[jb][5] += c2.y; vsum[jb][6] += c2.z; vsum[jb][7] += c2.w;
            }
        }
    }

    float sacc[NJB][8];
    #pragma unroll
    for (int jb = 0; jb < NJB; jb++)
        #pragma unroll
        for (int h2 = 0; h2 < 8; h2++) sacc[jb][h2] = 0.f;

    for (int ii = 0; ii < IC; ii++) {
        const int i = i0 + ii;
        __syncthreads();   // protect LDS reuse from previous iteration

        // Stage W[i] (4096 floats) into padded LDS rows; coalesced 16B/lane loads.
        {
            const float* wg = w + (size_t)i * (OO * DD * HH);
            #pragma unroll
            for (int j = 0; j < 4; j++) {
                const int c    = tid + j * 256;     // chunk of 4 floats, 0..1023
                float4 val     = *(const float4*)(wg + c * 4);
                const int orow = c >> 5;            // 32 chunks per 128-float row
                const int rr   = (c & 31) * 4;
                *(float4*)&Wsh[orow * WS + rr] = val;
            }
            if (tid < NBB * 2) {                    // stage u[bbase+.., i, :]
                const int bl = tid >> 1, q4 = (tid & 1) * 4;
                *(float4*)&Ush[bl * DD + q4] =
                    *(const float4*)(u + ((size_t)(bbase + bl) * II + i) * DD + q4);
            }
        }
        __syncthreads();

        // u values to registers (broadcast reads)
        float us[NJB][8];
        #pragma unroll
        for (int jb = 0; jb < NJB; jb++) {
            const int bl = bq * NJB + jb;
            float4 a = *(const float4*)&Ush[bl * DD];
            float4 c = *(const float4*)&Ush[bl * DD + 4];
            us[jb][0] = a.x; us[jb][1] = a.y; us[jb][2] = a.z; us[jb][3] = a.w;
            us[jb][4] = c.x; us[jb][5] = c.y; us[jb][6] = c.z; us[jb][7] = c.w;
        }

        // u_hat[b, i, o, h-half] = sum_d u[b,i,d] * W[i,o,d,h]
        float uh[NJB][8];
        #pragma unroll
        for (int jb = 0; jb < NJB; jb++)
            #pragma unroll
            for (int h2 = 0; h2 < 8; h2++) uh[jb][h2] = 0.f;
        #pragma unroll
        for (int d = 0; d < DD; d++) {
            const float* wp = &Wsh[o * WS + d * HH + hofs];
            float4 wa = *(const float4*)wp;
            float4 wb = *(const float4*)(wp + 4);
            const float wv[8] = {wa.x, wa.y, wa.z, wa.w, wb.x, wb.y, wb.z, wb.w};
            #pragma unroll
            for (int jb = 0; jb < NJB; jb++)
                #pragma unroll
                for (int h2 = 0; h2 < 8; h2++)
                    uh[jb][h2] = fmaf(us[jb][d], wv[h2], uh[jb][h2]);
        }

        // coupling coefficients
        float cc[NJB];
        if (PASS == 0) {
            #pragma unroll
            for (int jb = 0; jb < NJB; jb++) cc[jb] = 1.0f / 32.0f;
        } else {
            #pragma unroll
            for (int jb = 0; jb < NJB; jb++) {
                float lg = 0.f;
                #pragma unroll
                for (int h2 = 0; h2 < 8; h2++)
                    lg = fmaf(vsum[jb][h2], uh[jb][h2], lg);
                lg += __shfl_xor(lg, 32, 64);          // combine h-halves
                // softmax over o (lanes 0..31 in each half). |lg| small -> no max-sub.
                const float e = __expf(lg);
                float se = e;
                #pragma unroll
                for (int off = 16; off >= 1; off >>= 1)
                    se += __shfl_xor(se, off, 64);
                cc[jb] = __fdividef(e, se);
            }
        }

        #pragma unroll
        for (int jb = 0; jb < NJB; jb++)
            #pragma unroll
            for (int h2 = 0; h2 < 8; h2++)
                sacc[jb][h2] = fmaf(cc[jb], uh[jb][h2], sacc[jb][h2]);
    }

    // emit partial s
    #pragma unroll
    for (int jb = 0; jb < NJB; jb++) {
        const int b = bbase + bq * NJB + jb;
        if (ATOMIC) {
            float* p = out + ((b * OO + o) * HH + hofs);
            #pragma unroll
            for (int h2 = 0; h2 < 8; h2++) atomicAdd(p + h2, sacc[jb][h2]);
        } else {
            // per-chunk slab: a wave covers fully-written contiguous 64B lines
            float* p = out + ((size_t)blockIdx.x * BB + b) * (OO * HH) + o * HH + hofs;
            *(float4*)p       = make_float4(sacc[jb][0], sacc[jb][1], sacc[jb][2], sacc[jb][3]);
            *(float4*)(p + 4) = make_float4(sacc[jb][4], sacc[jb][5], sacc[jb][6], sacc[jb][7]);
        }
    }
}

// Fused reduce-over-chunks + squash. 32768 threads, t -> (b,o,h); h = t & 15.
// part[ic][t] summed over ic (coalesced 256B/wave), then squash over the 16-lane
// h-group via shfl_xor(width 16). Deterministic (fixed order).
__global__ __launch_bounds__(256)
void reduce_squash_kernel(const float* __restrict__ part, float* __restrict__ v)
{
    const int t = blockIdx.x * blockDim.x + threadIdx.x;   // 0..BOH-1
    float acc = 0.f;
    #pragma unroll 8
    for (int ic = 0; ic < NIC; ic++)
        acc += part[(size_t)ic * BOH + t];
    float sq = acc * acc;
    #pragma unroll
    for (int off = 8; off >= 1; off >>= 1)
        sq += __shfl_xor(sq, off, 16);
    const float scale = (sq / (1.f + sq)) * rsqrtf(sq + 1e-8f);
    v[t] = acc * scale;
}

// Standalone squash for the atomic-fallback path.
__global__ __launch_bounds__(256)
void squash_kernel(const float* __restrict__ s, float* __restrict__ v)
{
    const int t = blockIdx.x * blockDim.x + threadIdx.x;
    if (t >= BB * OO) return;
    const float4* sp = (const float4*)(s + t * HH);
    float4 a = sp[0], b = sp[1], c = sp[2], d = sp[3];
    float sq = a.x*a.x + a.y*a.y + a.z*a.z + a.w*a.w
             + b.x*b.x + b.y*b.y + b.z*b.z + b.w*b.w
             + c.x*c.x + c.y*c.y + c.z*c.z + c.w*c.w
             + d.x*d.x + d.y*d.y + d.z*d.z + d.w*d.w;
    const float scale = (sq / (1.f + sq)) * rsqrtf(sq + 1e-8f);
    a.x *= scale; a.y *= scale; a.z *= scale; a.w *= scale;
    b.x *= scale; b.y *= scale; b.z *= scale; b.w *= scale;
    c.x *= scale; c.y *= scale; c.z *= scale; c.w *= scale;
    d.x *= scale; d.y *= scale; d.z *= scale; d.w *= scale;
    float4* vp = (float4*)(v + t * HH);
    vp[0] = a; vp[1] = b; vp[2] = c; vp[3] = d;
}

extern "C" void kernel_launch(void* const* d_in, const int* in_sizes, int n_in,
                              void* d_out, int out_size, void* d_ws, size_t ws_size,
                              hipStream_t stream)
{
    (void)in_sizes; (void)n_in; (void)out_size;
    const float* u = (const float*)d_in[0];
    const float* w = (const float*)d_in[1];
    float* out = (float*)d_out;

    const dim3 grid(NIC, NBG), blk(256);
    const size_t need = ((size_t)NIC * BOH + 2 * BOH) * sizeof(float);  // ~16.3 MB

    if (ws_size >= need) {
        // Two-stage deterministic reduction (no atomics, no memsets).
        float* part = (float*)d_ws;                 // NIC x BOH partial s
        float* v0   = part + (size_t)NIC * BOH;
        float* v1   = v0 + BOH;
        const int rblocks = BOH / 256;              // 128

        pass_kernel<0, false><<<grid, blk, 0, stream>>>(u, w, nullptr, nullptr, part);
        reduce_squash_kernel<<<rblocks, 256, 0, stream>>>(part, v0);
        pass_kernel<1, false><<<grid, blk, 0, stream>>>(u, w, v0, nullptr, part);
        reduce_squash_kernel<<<rblocks, 256, 0, stream>>>(part, v1);
        pass_kernel<2, false><<<grid, blk, 0, stream>>>(u, w, v0, v1, part);
        reduce_squash_kernel<<<rblocks, 256, 0, stream>>>(part, out);
    } else {
        // Fallback: R1 atomic path (needs only 512 KB of ws).
        float* s0 = (float*)d_ws;
        float* s1 = s0 + BOH;
        float* v0 = s1 + BOH;
        float* v1 = v0 + BOH;
        hipMemsetAsync(d_ws, 0, 2 * BOH * sizeof(float), stream);
        hipMemsetAsync(d_out, 0, BOH * sizeof(float), stream);
        const int sq_blocks = (BB * OO + 255) / 256;

        pass_kernel<0, true><<<grid, blk, 0, stream>>>(u, w, nullptr, nullptr, s0);
        squash_kernel<<<sq_blocks, 256, 0, stream>>>(s0, v0);
        pass_kernel<1, true><<<grid, blk, 0, stream>>>(u, w, v0, nullptr, s1);
        squash_kernel<<<sq_blocks, 256, 0, stream>>>(s1, v1);
        pass_kernel<2, true><<<grid, blk, 0, stream>>>(u, w, v0, v1, out);
        squash_kernel<<<sq_blocks, 256, 0, stream>>>(out, out);
    }
}